// Round 8
// baseline (663.821 us; speedup 1.0000x reference)
//
#include <hip/hip_runtime.h>

// MonarchLinear — ROUND 8 DIAGNOSTIC (dur_us intentionally inflated).
// Seven variants all land 130-153us; no component model explains it and our
// dispatches never crack rocprof top-5 (harness fills at ~175us dominate).
// This round repeats stage1 x8 and stage2 x5 IN-KERNEL (identical output,
// rep*zero address offsets defeat hoisting/DSE) so both dispatches run
// 200-600us and surface in top-5 with full counters:
//   T1 = dur(stage1_rep)/8, T2 = dur(stage2_rep)/5
//   stage2_rep: WRITE ~1.56GB; FETCH ~= WRITE  -> RFO/write-allocate smoking gun
//   high VALUBusy on either stage -> issue-side, not drain-side
//   SQ_LDS_BANK_CONFLICT tells if the b128 t1 reads (m vs m+8 alias) matter.

typedef float f4 __attribute__((ext_vector_type(4)));

namespace {
constexpr int MM     = 68;
constexpr int IN_D   = 256;
constexpr int OUT_D  = 4608;
constexpr int T_TILE = 16;
constexpr int NTH    = 256;
constexpr int NJ     = 5;
constexpr int T1W    = 4 * MM;    // 272 floats per token in t1
constexpr int REP1   = 8;
constexpr int REP2   = 5;
}

// ---------------- stage 1 (x@L -> t1), repeated REP times ----------------
template <int REP>
__global__ __launch_bounds__(NTH, 6)
void monarch_stage1(const float* __restrict__ x, const float* __restrict__ L,
                    float* __restrict__ t1ws, int zero)
{
  __shared__ float t1s[T_TILE * T1W];
  const int tid = threadIdx.x;
  const long tb = (long)blockIdx.x * T_TILE;

#pragma unroll 1
  for (int rep = 0; rep < REP; ++rep) {
    const float* xb = x    + rep * zero;     // zero==0 at runtime; defeats hoist/DSE
    float*       wb = t1ws + rep * zero;
    __syncthreads();
    for (int idx = tid; idx < T1W; idx += NTH) {
      const int r = idx / MM;
      const float* Lp = L + (size_t)idx * MM;
      const float* xp = xb + tb * IN_D + r * MM;
      const int p4max = (r == 3) ? (IN_D - 3 * MM) / 4 : MM / 4;   // 13 or 17
      float acc[T_TILE];
#pragma unroll
      for (int t = 0; t < T_TILE; ++t) acc[t] = 0.f;
      for (int p4 = 0; p4 < p4max; ++p4) {
        f4 Lv = *(const f4*)(Lp + p4 * 4);
#pragma unroll
        for (int t = 0; t < T_TILE; ++t) {
          f4 xv = *(const f4*)(xp + (size_t)t * IN_D + p4 * 4);
          acc[t] = fmaf(Lv.x, xv.x, acc[t]);
          acc[t] = fmaf(Lv.y, xv.y, acc[t]);
          acc[t] = fmaf(Lv.z, xv.z, acc[t]);
          acc[t] = fmaf(Lv.w, xv.w, acc[t]);
        }
      }
#pragma unroll
      for (int t = 0; t < T_TILE; ++t) t1s[t * T1W + idx] = acc[t];
    }
    __syncthreads();
    float* wp = wb + tb * T1W;
#pragma unroll
    for (int k = 0; k < (T_TILE * T1W) / NTH; ++k)
      wp[tid + k * NTH] = t1s[tid + k * NTH];
  }
}

// ---------------- stage 2 (t1@R -> out), j outer, repeated REP times ----------------
template <int REP>
__global__ __launch_bounds__(NTH, 4)
void monarch_stage2(const float* __restrict__ t1ws, const float* __restrict__ R,
                    const float* __restrict__ bias, float* __restrict__ out,
                    int zero)
{
  __shared__ float t1s[T_TILE * T1W];
  const int tid = threadIdx.x;
  const long tb = (long)blockIdx.x * T_TILE;

  const int g  = tid / 17;
  const int m  = tid - g * 17;
  const int l4 = 4 * m;

#pragma unroll 1
  for (int rep = 0; rep < REP; ++rep) {
    const float* rb = t1ws + rep * zero;
    float*       ob = out  + rep * zero;
    __syncthreads();
    const float* rp = rb + tb * T1W;
#pragma unroll
    for (int k = 0; k < (T_TILE * T1W) / NTH; ++k)
      t1s[tid + k * NTH] = rp[tid + k * NTH];
    __syncthreads();

#pragma unroll 1                       // j rolled: 20 hoisted regs per iter
    for (int j = 0; j < NJ; ++j) {
      const int s = g + 15 * j;
      const bool act = (tid < 255) && (s < MM) && (s < MM - 1 || m < 13);
      const int scol = s * MM + l4;
      f4 R0, R1, R2, R3, bv;
      if (act) {
        R0 = *(const f4*)(R + (size_t)(l4 + 0) * (MM * MM) + (size_t)s * MM);
        R1 = *(const f4*)(R + (size_t)(l4 + 1) * (MM * MM) + (size_t)s * MM);
        R2 = *(const f4*)(R + (size_t)(l4 + 2) * (MM * MM) + (size_t)s * MM);
        R3 = *(const f4*)(R + (size_t)(l4 + 3) * (MM * MM) + (size_t)s * MM);
        bv = *(const f4*)(bias + scol);
      }
#pragma unroll 2
      for (int t = 0; t < T_TILE; ++t) {
        if (act) {
          const float* t1p = t1s + t * T1W + l4;
          f4 a0 = *(const f4*)(t1p);
          f4 a1 = *(const f4*)(t1p + MM);
          f4 a2 = *(const f4*)(t1p + 2 * MM);
          f4 a3 = *(const f4*)(t1p + 3 * MM);
          f4 o;
          o.x = fmaf(a3.x, R0.w, fmaf(a2.x, R0.z, fmaf(a1.x, R0.y, fmaf(a0.x, R0.x, bv.x))));
          o.y = fmaf(a3.y, R1.w, fmaf(a2.y, R1.z, fmaf(a1.y, R1.y, fmaf(a0.y, R1.x, bv.y))));
          o.z = fmaf(a3.z, R2.w, fmaf(a2.z, R2.z, fmaf(a1.z, R2.y, fmaf(a0.z, R2.x, bv.z))));
          o.w = fmaf(a3.w, R3.w, fmaf(a2.w, R3.z, fmaf(a1.w, R3.y, fmaf(a0.w, R3.x, bv.w))));
          *(f4*)(ob + (tb + t) * OUT_D + scol) = o;
        }
      }
    }
  }
}

// ---------------- fused fallback (ws too small) ----------------
__global__ __launch_bounds__(NTH, 2)
void monarch_fused(const float* __restrict__ x, const float* __restrict__ L,
                   const float* __restrict__ R, const float* __restrict__ bias,
                   float* __restrict__ out)
{
  __shared__ float t1s[T_TILE * T1W];
  const int tid = threadIdx.x;
  const long tb = (long)blockIdx.x * T_TILE;
  const int g  = tid / 17;
  const int m  = tid - g * 17;
  const int l4 = 4 * m;

  for (int idx = tid; idx < T1W; idx += NTH) {
    const int r = idx / MM;
    const float* Lp = L + (size_t)idx * MM;
    const float* xp = x + tb * IN_D + r * MM;
    const int p4max = (r == 3) ? (IN_D - 3 * MM) / 4 : MM / 4;
    float acc[T_TILE];
#pragma unroll
    for (int t = 0; t < T_TILE; ++t) acc[t] = 0.f;
    for (int p4 = 0; p4 < p4max; ++p4) {
      f4 Lv = *(const f4*)(Lp + p4 * 4);
#pragma unroll
      for (int t = 0; t < T_TILE; ++t) {
        f4 xv = *(const f4*)(xp + (size_t)t * IN_D + p4 * 4);
        acc[t] = fmaf(Lv.x, xv.x, acc[t]);
        acc[t] = fmaf(Lv.y, xv.y, acc[t]);
        acc[t] = fmaf(Lv.z, xv.z, acc[t]);
        acc[t] = fmaf(Lv.w, xv.w, acc[t]);
      }
    }
#pragma unroll
    for (int t = 0; t < T_TILE; ++t) t1s[t * T1W + idx] = acc[t];
  }
  __syncthreads();

#pragma unroll 1
  for (int j = 0; j < NJ; ++j) {
    const int s = g + 15 * j;
    const bool act = (tid < 255) && (s < MM) && (s < MM - 1 || m < 13);
    const int scol = s * MM + l4;
    f4 R0, R1, R2, R3, bv;
    if (act) {
      R0 = *(const f4*)(R + (size_t)(l4 + 0) * (MM * MM) + (size_t)s * MM);
      R1 = *(const f4*)(R + (size_t)(l4 + 1) * (MM * MM) + (size_t)s * MM);
      R2 = *(const f4*)(R + (size_t)(l4 + 2) * (MM * MM) + (size_t)s * MM);
      R3 = *(const f4*)(R + (size_t)(l4 + 3) * (MM * MM) + (size_t)s * MM);
      bv = *(const f4*)(bias + scol);
    }
#pragma unroll 2
    for (int t = 0; t < T_TILE; ++t) {
      if (act) {
        const float* t1p = t1s + t * T1W + l4;
        f4 a0 = *(const f4*)(t1p);
        f4 a1 = *(const f4*)(t1p + MM);
        f4 a2 = *(const f4*)(t1p + 2 * MM);
        f4 a3 = *(const f4*)(t1p + 3 * MM);
        f4 o;
        o.x = fmaf(a3.x, R0.w, fmaf(a2.x, R0.z, fmaf(a1.x, R0.y, fmaf(a0.x, R0.x, bv.x))));
        o.y = fmaf(a3.y, R1.w, fmaf(a2.y, R1.z, fmaf(a1.y, R1.y, fmaf(a0.y, R1.x, bv.y))));
        o.z = fmaf(a3.z, R2.w, fmaf(a2.z, R2.z, fmaf(a1.z, R2.y, fmaf(a0.z, R2.x, bv.z))));
        o.w = fmaf(a3.w, R3.w, fmaf(a2.w, R3.z, fmaf(a1.w, R3.y, fmaf(a0.w, R3.x, bv.w))));
        *(f4*)(out + (tb + t) * OUT_D + scol) = o;
      }
    }
  }
}

extern "C" void kernel_launch(void* const* d_in, const int* in_sizes, int n_in,
                              void* d_out, int out_size, void* d_ws, size_t ws_size,
                              hipStream_t stream) {
  const float* x    = (const float*)d_in[0];
  const float* L    = (const float*)d_in[1];
  const float* R    = (const float*)d_in[2];
  const float* bias = (const float*)d_in[3];
  float* out = (float*)d_out;

  const int ntok   = in_sizes[0] / IN_D;                    // 16384
  const int nblk   = ntok / T_TILE;                         // 1024
  const size_t t1b = (size_t)ntok * T1W * sizeof(float);    // 17.8 MB

  if (ws_size >= t1b) {
    float* t1ws = (float*)d_ws;
    monarch_stage1<REP1><<<nblk, NTH, 0, stream>>>(x, L, t1ws, 0);
    monarch_stage2<REP2><<<nblk, NTH, 0, stream>>>(t1ws, R, bias, out, 0);
  } else {
    monarch_fused<<<nblk, NTH, 0, stream>>>(x, L, R, bias, out);
  }
}

// Round 9
// 351.887 us; speedup vs baseline: 1.8865x; 1.8865x over previous
//
#include <hip/hip_runtime.h>

// MonarchLinear: x[16384,256] fp32, L[68,68,68], R[68,68,68], bias[4608] -> out[16384,4608] fp32.
//   t1[b,r,l] = sum_p x[b, r*68+p] * L[r,l,p]           (r<4; r==3 only p<52 valid)
//   out[b, s*68+l] = sum_{r<4} t1[b,r,l] * R[l,s,r] + bias[s*68+l]
//
// Round 9: round-8 diagnostic showed T1=54us (issue-bound: 64-line L scatters,
// VGPR=32 load-use serialization), T2=47us (= write roofline). New fused kernel:
//  - phase A: thread=(tok, r, q-quarter); r is WAVE-UNIFORM -> L loads touch <=2
//    lines/instr; x-segment register-resident (fully unrolled, constant idx);
//    t1 -> LDS with +1-row pad (stride 273 => 17*tok mod 32: conflict-free).
//  - phase B: proven round-7 stage-2 body (j-outer, 20 hoisted regs, contiguous
//    f4 stores), t1 straight from LDS (no HBM round-trip, no 2nd launch).
// 512 thr x 32 tok, grid 512 (2 blocks/CU, 4 waves/SIMD, LDS 34.9KB/block).

typedef float f4 __attribute__((ext_vector_type(4)));

namespace {
constexpr int MM    = 68;
constexpr int IN_D  = 256;
constexpr int OUT_D = 4608;
constexpr int TT    = 32;      // tokens per block
constexpr int NTH   = 512;
constexpr int PADW  = 4 * MM + 1;   // 273: +1 pad -> stage-A writes hit all 32 banks
}

// phase-A worker: dot(x-segment, L-rows) for one (r, q-quarter), P4MAX compile-time
// so xr[] indexing is constant (runtime-indexed ext_vector arrays go to scratch).
template <int P4MAX>
__device__ __forceinline__ void stage1_work(const float* __restrict__ xp,
                                            const float* __restrict__ Lrow0,
                                            float* __restrict__ wp, int nq4)
{
  f4 xr[P4MAX];
#pragma unroll
  for (int p4 = 0; p4 < P4MAX; ++p4) xr[p4] = *(const f4*)(xp + 4 * p4);

#pragma unroll 1
  for (int qo = 0; qo < nq4; ++qo) {
    f4 o4;
#pragma unroll
    for (int qi = 0; qi < 4; ++qi) {
      const float* Lp = Lrow0 + (size_t)(qo * 4 + qi) * MM;
      f4 s4 = {0.f, 0.f, 0.f, 0.f};
#pragma unroll
      for (int p4 = 0; p4 < P4MAX; ++p4) {
        f4 Lv = *(const f4*)(Lp + 4 * p4);
        s4.x = fmaf(xr[p4].x, Lv.x, s4.x);
        s4.y = fmaf(xr[p4].y, Lv.y, s4.y);
        s4.z = fmaf(xr[p4].z, Lv.z, s4.z);
        s4.w = fmaf(xr[p4].w, Lv.w, s4.w);
      }
      o4[qi] = (s4.x + s4.y) + (s4.z + s4.w);
    }
    *(f4*)(wp + 4 * qo) = o4;   // b128, lanes spread over all 32 banks (pad 273)
  }
}

__global__ __launch_bounds__(NTH, 4)
void monarch_v3(const float* __restrict__ x, const float* __restrict__ L,
                const float* __restrict__ R, const float* __restrict__ bias,
                float* __restrict__ out)
{
  __shared__ float t1s[TT * PADW];   // 34,944 B
  const int tid = threadIdx.x;
  const long tb = (long)blockIdx.x * TT;

  // ---------------- phase A: x @ L^T -> t1s ----------------
  {
    const int tok   = tid & 31;
    const int combo = tid >> 5;            // 0..15; wave = 2 combos -> r uniform
    const int r     = combo >> 2;
    const int qq    = combo & 3;
    const int qbase = (qq == 0) ? 0 : (4 + 16 * qq);   // 0,20,36,52
    const int nq4   = (qq == 0) ? 5 : 4;               // 20/16 q's, f4-aligned

    const float* xp    = x + (tb + tok) * IN_D + r * MM;
    const float* Lrow0 = L + (size_t)(r * MM + qbase) * MM;
    float*       wp    = &t1s[tok * PADW + r * MM + qbase];

    if (r < 3) stage1_work<17>(xp, Lrow0, wp, nq4);   // full 68-dot
    else       stage1_work<13>(xp, Lrow0, wp, nq4);   // r==3: p<52 (rest is pad)
  }
  __syncthreads();

  // ---------------- phase B: t1s @ R + bias -> out ----------------
  {
    const int v  = tid & 255;
    const int tt = tid >> 8;               // token half: 0 -> t 0..15, 1 -> 16..31
    const int g  = v / 17;
    const int m  = v - g * 17;
    const int l4 = 4 * m;

#pragma unroll 1                            // j rolled: 20 hoisted regs per iter
    for (int j = 0; j < 5; ++j) {
      const int s = g + 15 * j;
      // v==255 (g==15,m==0) duplicates (g=0,j+1); s==67 row has only 52 cols (m<13)
      const bool act = (v < 255) && (s < MM) && (s < MM - 1 || m < 13);
      const int scol = s * MM + l4;
      f4 R0, R1, R2, R3, bv;
      if (act) {
        R0 = *(const f4*)(R + (size_t)(l4 + 0) * (MM * MM) + (size_t)s * MM);
        R1 = *(const f4*)(R + (size_t)(l4 + 1) * (MM * MM) + (size_t)s * MM);
        R2 = *(const f4*)(R + (size_t)(l4 + 2) * (MM * MM) + (size_t)s * MM);
        R3 = *(const f4*)(R + (size_t)(l4 + 3) * (MM * MM) + (size_t)s * MM);
        bv = *(const f4*)(bias + scol);
      }
#pragma unroll 2
      for (int ti = 0; ti < TT / 2; ++ti) {
        const int t = tt * (TT / 2) + ti;
        if (act) {
          const float* t1p = t1s + t * PADW + l4;
          f4 a0 = *(const f4*)(t1p);
          f4 a1 = *(const f4*)(t1p + MM);
          f4 a2 = *(const f4*)(t1p + 2 * MM);
          f4 a3 = *(const f4*)(t1p + 3 * MM);
          f4 o;
          o.x = fmaf(a3.x, R0.w, fmaf(a2.x, R0.z, fmaf(a1.x, R0.y, fmaf(a0.x, R0.x, bv.x))));
          o.y = fmaf(a3.y, R1.w, fmaf(a2.y, R1.z, fmaf(a1.y, R1.y, fmaf(a0.y, R1.x, bv.y))));
          o.z = fmaf(a3.z, R2.w, fmaf(a2.z, R2.z, fmaf(a1.z, R2.y, fmaf(a0.z, R2.x, bv.z))));
          o.w = fmaf(a3.w, R3.w, fmaf(a2.w, R3.z, fmaf(a1.w, R3.y, fmaf(a0.w, R3.x, bv.w))));
          *(f4*)(out + (tb + t) * OUT_D + scol) = o;
        }
      }
    }
  }
}

extern "C" void kernel_launch(void* const* d_in, const int* in_sizes, int n_in,
                              void* d_out, int out_size, void* d_ws, size_t ws_size,
                              hipStream_t stream) {
  const float* x    = (const float*)d_in[0];
  const float* L    = (const float*)d_in[1];
  const float* R    = (const float*)d_in[2];
  const float* bias = (const float*)d_in[3];
  float* out = (float*)d_out;

  const int ntok = in_sizes[0] / IN_D;     // 16384
  const int nblk = ntok / TT;              // 512 blocks x 512 threads
  monarch_v3<<<nblk, NTH, 0, stream>>>(x, L, R, bias, out);
}

// Round 10
// 337.684 us; speedup vs baseline: 1.9658x; 1.0421x over previous
//
#include <hip/hip_runtime.h>

// MonarchLinear: x[16384,256] fp32, L[68,68,68], R[68,68,68], bias[4608] -> out[16384,4608] fp32.
//   t1[b,r,l] = sum_p x[b, r*68+p] * L[r,l,p]           (r<4; r==3 only p<52 valid)
//   out[b, s*68+l] = sum_{r<4} t1[b,r,l] * R[l,s,r] + bias[s*68+l]
//
// Round 10: split (round-8 proved stage2 at write roofline, 46.6us). Stage 1
// rebuilt: round-9's fused attempt scattered x (lane=token, 1024B stride) and
// let the 302MB write stream thrash L2+L3 (FETCH 610MB). Now: x staged to LDS
// with coalesced f4 sweeps; compute threads = (tok, r, qq) with r WAVE-UNIFORM
// so L loads are 4-address broadcasts; x segment register-resident; t1 via LDS
// -> contiguous global copy. Stage 2 = round-7/8 body verbatim (roofline).

typedef float f4 __attribute__((ext_vector_type(4)));

namespace {
constexpr int MM    = 68;
constexpr int IN_D  = 256;
constexpr int OUT_D = 4608;
constexpr int TT1   = 16;          // tokens per block, stage 1
constexpr int NTH   = 256;
constexpr int NJ    = 5;
constexpr int T1W   = 4 * MM;      // 272 floats per token in t1
constexpr int XROW  = IN_D + 4;    // 260: padded x row stride in LDS (bank spread)
}

// ---- stage-1 dot worker: P4MAX compile-time so xr[] stays in registers ----
template <int P4MAX>
__device__ __forceinline__ void s1_dot(const float* __restrict__ xls,
                                       const float* __restrict__ Lrow0,
                                       float* __restrict__ t1w, int nq4)
{
  f4 xr[P4MAX];
#pragma unroll
  for (int p4 = 0; p4 < P4MAX; ++p4) xr[p4] = *(const f4*)(xls + 4 * p4);

#pragma unroll 1
  for (int qo = 0; qo < nq4; ++qo) {
    f4 o4;
#pragma unroll
    for (int qi = 0; qi < 4; ++qi) {
      const float* Lp = Lrow0 + (size_t)(qo * 4 + qi) * MM;
      f4 s4 = {0.f, 0.f, 0.f, 0.f};
#pragma unroll
      for (int p4 = 0; p4 < P4MAX; ++p4) {
        f4 Lv = *(const f4*)(Lp + 4 * p4);     // 4-address broadcast per wave
        s4.x = fmaf(xr[p4].x, Lv.x, s4.x);
        s4.y = fmaf(xr[p4].y, Lv.y, s4.y);
        s4.z = fmaf(xr[p4].z, Lv.z, s4.z);
        s4.w = fmaf(xr[p4].w, Lv.w, s4.w);
      }
      o4[qi] = (s4.x + s4.y) + (s4.z + s4.w);
    }
    *(f4*)(t1w + 4 * qo) = o4;
  }
}

// ---------------- stage 1: x @ L^T -> t1ws ----------------
__global__ __launch_bounds__(NTH, 4)
void monarch_s1(const float* __restrict__ x, const float* __restrict__ L,
                float* __restrict__ t1ws)
{
  __shared__ float xs[TT1 * XROW];    // 16,640 B
  __shared__ float t1s[TT1 * T1W];    // 17,408 B
  const int tid = threadIdx.x;
  const long tb = (long)blockIdx.x * TT1;

  // coalesced x -> LDS: 16 rows x 64 f4, 4 full-width sweeps
#pragma unroll
  for (int k = 0; k < (TT1 * IN_D / 4) / NTH; ++k) {
    int i   = k * NTH + tid;          // f4 index
    int tok = i >> 6;                 // 64 f4 per token row
    int pos = i & 63;
    f4 v = *(const f4*)(x + (tb + tok) * IN_D + 4 * pos);
    *(f4*)(&xs[tok * XROW + 4 * pos]) = v;
  }
  __syncthreads();

  {
    const int tok   = tid & 15;
    const int combo = tid >> 4;        // wave = 4 combos, SAME r (wave-uniform)
    const int r     = combo >> 2;
    const int qq    = combo & 3;
    const int qbase = (qq == 0) ? 0 : (4 + 16 * qq);   // 0,20,36,52
    const int nq4   = (qq == 0) ? 5 : 4;

    const float* xls   = &xs[tok * XROW + r * MM];
    const float* Lrow0 = L + (size_t)(r * MM + qbase) * MM;
    float*       t1w   = &t1s[tok * T1W + r * MM + qbase];

    if (r < 3) s1_dot<17>(xls, Lrow0, t1w, nq4);   // full 68-dot
    else       s1_dot<13>(xls, Lrow0, t1w, nq4);   // r==3: p<52 valid
  }
  __syncthreads();

  // contiguous LDS -> global copy (17 sweeps of 1KB)
  float* wp = t1ws + tb * T1W;
#pragma unroll
  for (int k = 0; k < (TT1 * T1W) / NTH; ++k)
    wp[k * NTH + tid] = t1s[k * NTH + tid];
}

// ---------------- stage 2: t1 @ R + bias -> out (round-7/8 body, roofline) ----------------
__global__ __launch_bounds__(NTH, 4)
void monarch_s2(const float* __restrict__ t1ws, const float* __restrict__ R,
                const float* __restrict__ bias, float* __restrict__ out)
{
  __shared__ float t1s[TT1 * T1W];
  const int tid = threadIdx.x;
  const long tb = (long)blockIdx.x * TT1;

  const int g  = tid / 17;
  const int m  = tid - g * 17;
  const int l4 = 4 * m;

  const float* rp = t1ws + tb * T1W;
#pragma unroll
  for (int k = 0; k < (TT1 * T1W) / NTH; ++k)
    t1s[tid + k * NTH] = rp[tid + k * NTH];
  __syncthreads();

#pragma unroll 1                       // j rolled: 20 hoisted regs per iter
  for (int j = 0; j < NJ; ++j) {
    const int s = g + 15 * j;
    // tid==255 (g==15,m==0) duplicates (g=0,j+1); s==67 row has only 52 cols (m<13)
    const bool act = (tid < 255) && (s < MM) && (s < MM - 1 || m < 13);
    const int scol = s * MM + l4;
    f4 R0, R1, R2, R3, bv;
    if (act) {
      R0 = *(const f4*)(R + (size_t)(l4 + 0) * (MM * MM) + (size_t)s * MM);
      R1 = *(const f4*)(R + (size_t)(l4 + 1) * (MM * MM) + (size_t)s * MM);
      R2 = *(const f4*)(R + (size_t)(l4 + 2) * (MM * MM) + (size_t)s * MM);
      R3 = *(const f4*)(R + (size_t)(l4 + 3) * (MM * MM) + (size_t)s * MM);
      bv = *(const f4*)(bias + scol);
    }
#pragma unroll 2
    for (int t = 0; t < TT1; ++t) {
      if (act) {
        const float* t1p = t1s + t * T1W + l4;
        f4 a0 = *(const f4*)(t1p);
        f4 a1 = *(const f4*)(t1p + MM);
        f4 a2 = *(const f4*)(t1p + 2 * MM);
        f4 a3 = *(const f4*)(t1p + 3 * MM);
        f4 o;
        o.x = fmaf(a3.x, R0.w, fmaf(a2.x, R0.z, fmaf(a1.x, R0.y, fmaf(a0.x, R0.x, bv.x))));
        o.y = fmaf(a3.y, R1.w, fmaf(a2.y, R1.z, fmaf(a1.y, R1.y, fmaf(a0.y, R1.x, bv.y))));
        o.z = fmaf(a3.z, R2.w, fmaf(a2.z, R2.z, fmaf(a1.z, R2.y, fmaf(a0.z, R2.x, bv.z))));
        o.w = fmaf(a3.w, R3.w, fmaf(a2.w, R3.z, fmaf(a1.w, R3.y, fmaf(a0.w, R3.x, bv.w))));
        *(f4*)(out + (tb + t) * OUT_D + scol) = o;
      }
    }
  }
}

// ---------------- fused fallback (ws too small; round-7 body) ----------------
__global__ __launch_bounds__(NTH, 2)
void monarch_fused(const float* __restrict__ x, const float* __restrict__ L,
                   const float* __restrict__ R, const float* __restrict__ bias,
                   float* __restrict__ out)
{
  __shared__ float t1s[TT1 * T1W];
  const int tid = threadIdx.x;
  const long tb = (long)blockIdx.x * TT1;
  const int g  = tid / 17;
  const int m  = tid - g * 17;
  const int l4 = 4 * m;

  for (int idx = tid; idx < T1W; idx += NTH) {
    const int r = idx / MM;
    const float* Lp = L + (size_t)idx * MM;
    const float* xp = x + tb * IN_D + r * MM;
    const int p4max = (r == 3) ? (IN_D - 3 * MM) / 4 : MM / 4;
    float acc[TT1];
#pragma unroll
    for (int t = 0; t < TT1; ++t) acc[t] = 0.f;
    for (int p4 = 0; p4 < p4max; ++p4) {
      f4 Lv = *(const f4*)(Lp + p4 * 4);
#pragma unroll
      for (int t = 0; t < TT1; ++t) {
        f4 xv = *(const f4*)(xp + (size_t)t * IN_D + p4 * 4);
        acc[t] = fmaf(Lv.x, xv.x, acc[t]);
        acc[t] = fmaf(Lv.y, xv.y, acc[t]);
        acc[t] = fmaf(Lv.z, xv.z, acc[t]);
        acc[t] = fmaf(Lv.w, xv.w, acc[t]);
      }
    }
#pragma unroll
    for (int t = 0; t < TT1; ++t) t1s[t * T1W + idx] = acc[t];
  }
  __syncthreads();

#pragma unroll 1
  for (int j = 0; j < NJ; ++j) {
    const int s = g + 15 * j;
    const bool act = (tid < 255) && (s < MM) && (s < MM - 1 || m < 13);
    const int scol = s * MM + l4;
    f4 R0, R1, R2, R3, bv;
    if (act) {
      R0 = *(const f4*)(R + (size_t)(l4 + 0) * (MM * MM) + (size_t)s * MM);
      R1 = *(const f4*)(R + (size_t)(l4 + 1) * (MM * MM) + (size_t)s * MM);
      R2 = *(const f4*)(R + (size_t)(l4 + 2) * (MM * MM) + (size_t)s * MM);
      R3 = *(const f4*)(R + (size_t)(l4 + 3) * (MM * MM) + (size_t)s * MM);
      bv = *(const f4*)(bias + scol);
    }
#pragma unroll 2
    for (int t = 0; t < TT1; ++t) {
      if (act) {
        const float* t1p = t1s + t * T1W + l4;
        f4 a0 = *(const f4*)(t1p);
        f4 a1 = *(const f4*)(t1p + MM);
        f4 a2 = *(const f4*)(t1p + 2 * MM);
        f4 a3 = *(const f4*)(t1p + 3 * MM);
        f4 o;
        o.x = fmaf(a3.x, R0.w, fmaf(a2.x, R0.z, fmaf(a1.x, R0.y, fmaf(a0.x, R0.x, bv.x))));
        o.y = fmaf(a3.y, R1.w, fmaf(a2.y, R1.z, fmaf(a1.y, R1.y, fmaf(a0.y, R1.x, bv.y))));
        o.z = fmaf(a3.z, R2.w, fmaf(a2.z, R2.z, fmaf(a1.z, R2.y, fmaf(a0.z, R2.x, bv.z))));
        o.w = fmaf(a3.w, R3.w, fmaf(a2.w, R3.z, fmaf(a1.w, R3.y, fmaf(a0.w, R3.x, bv.w))));
        *(f4*)(out + (tb + t) * OUT_D + scol) = o;
      }
    }
  }
}

extern "C" void kernel_launch(void* const* d_in, const int* in_sizes, int n_in,
                              void* d_out, int out_size, void* d_ws, size_t ws_size,
                              hipStream_t stream) {
  const float* x    = (const float*)d_in[0];
  const float* L    = (const float*)d_in[1];
  const float* R    = (const float*)d_in[2];
  const float* bias = (const float*)d_in[3];
  float* out = (float*)d_out;

  const int ntok   = in_sizes[0] / IN_D;                    // 16384
  const int nblk   = ntok / TT1;                            // 1024
  const size_t t1b = (size_t)ntok * T1W * sizeof(float);    // 17.8 MB

  if (ws_size >= t1b) {
    float* t1ws = (float*)d_ws;
    monarch_s1<<<nblk, NTH, 0, stream>>>(x, L, t1ws);
    monarch_s2<<<nblk, NTH, 0, stream>>>(t1ws, R, bias, out);
  } else {
    monarch_fused<<<nblk, NTH, 0, stream>>>(x, L, R, bias, out);
  }
}

// Round 11
// 169.378 us; speedup vs baseline: 3.9192x; 1.9937x over previous
//
#include <hip/hip_runtime.h>

// MonarchLinear: x[16384,256] fp32, L[68,68,68], R[68,68,68], bias[4608] -> out[16384,4608] fp32.
//   t1[b,r,l] = sum_p x[b, r*68+p] * L[r,l,p]           (r<4; r==3 only p<52 valid)
//   out[b, s*68+l] = sum_{r<4} t1[b,r,l] * R[l,s,r] + bias[s*68+l]
//
// Round 11. Facts: stage2 (round-7 body) = 46.6us = write roofline (round-8 rep
// measurement). Old stage1 = 54us, latency-bound: lane-scattered L reads (74KB
// slice > 32KB L1) serialize ~200cy L2 round trips. Round-10's reg-resident fix
// SPILLED (VGPR=64 < xr's 68; 332MB scratch writes). This round: stage L slice
// into LDS by a LINEAR copy (coalesced, aligned, conflict-free), keep the simple
// thread=l-row / acc[tokens] structure; Lv from LDS kills the latency chain.
// NTH=320 -> all 272 rows in ONE round (no serial tail). TT=32, grid 512.

typedef float f4 __attribute__((ext_vector_type(4)));

namespace {
constexpr int MM    = 68;
constexpr int IN_D  = 256;
constexpr int OUT_D = 4608;
constexpr int T1W   = 4 * MM;      // 272 floats per token in t1
constexpr int LSLC  = T1W * MM;    // 18,496 floats: used L slice (73,984 B)
// stage 1
constexpr int TT1   = 32;
constexpr int NTH1  = 320;
// stage 2
constexpr int TT2   = 16;
constexpr int NTH2  = 256;
constexpr int NJ    = 5;
}

// ---------------- stage 1: x @ L^T -> t1ws (L staged in LDS) ----------------
__global__ __launch_bounds__(NTH1, 2)
void monarch_s1(const float* __restrict__ x, const float* __restrict__ L,
                float* __restrict__ t1ws)
{
  __shared__ float Lsh[LSLC];              // 73,984 B; rows stride 68 (272B, 16B-aligned)
  const int tid = threadIdx.x;
  const long tb = (long)blockIdx.x * TT1;

  // linear coalesced copy of the used L slice: 4624 f4
#pragma unroll
  for (int k = 0; k < (LSLC / 4 + NTH1 - 1) / NTH1; ++k) {
    int i = k * NTH1 + tid;
    if (i < LSLC / 4)
      *(f4*)(&Lsh[4 * i]) = *(const f4*)(L + 4 * (size_t)i);
  }
  __syncthreads();

  if (tid < T1W) {                         // one task per thread, no serial tail
    const int idx = tid;                   // = r*68 + l
    const int r   = idx / MM;
    const int p4m = (r == 3) ? (IN_D - 3 * MM) / 4 : MM / 4;   // 13 or 17
    const float* xp = x + tb * IN_D + r * MM;

    float acc[TT1];
#pragma unroll
    for (int t = 0; t < TT1; ++t) acc[t] = 0.f;

    for (int p4 = 0; p4 < p4m; ++p4) {
      f4 Lv = *(const f4*)(&Lsh[idx * MM + 4 * p4]);   // LDS, aligned b128
#pragma unroll
      for (int t = 0; t < TT1; ++t) {
        f4 xv = *(const f4*)(xp + (size_t)t * IN_D + 4 * p4);  // wave-broadcast, L1-hot
        acc[t] = fmaf(Lv.x, xv.x, acc[t]);
        acc[t] = fmaf(Lv.y, xv.y, acc[t]);
        acc[t] = fmaf(Lv.z, xv.z, acc[t]);
        acc[t] = fmaf(Lv.w, xv.w, acc[t]);
      }
    }
#pragma unroll
    for (int t = 0; t < TT1; ++t)          // 256B contiguous per wave-instr
      t1ws[(tb + t) * T1W + idx] = acc[t];
  }
}

// ---------------- stage 2: t1 @ R + bias -> out (round-7/8 body, at roofline) ----------------
__global__ __launch_bounds__(NTH2, 4)
void monarch_s2(const float* __restrict__ t1ws, const float* __restrict__ R,
                const float* __restrict__ bias, float* __restrict__ out)
{
  __shared__ float t1s[TT2 * T1W];
  const int tid = threadIdx.x;
  const long tb = (long)blockIdx.x * TT2;

  const int g  = tid / 17;
  const int m  = tid - g * 17;
  const int l4 = 4 * m;

  const float* rp = t1ws + tb * T1W;
#pragma unroll
  for (int k = 0; k < (TT2 * T1W) / NTH2; ++k)
    t1s[tid + k * NTH2] = rp[tid + k * NTH2];
  __syncthreads();

#pragma unroll 1                       // j rolled: 20 hoisted regs per iter
  for (int j = 0; j < NJ; ++j) {
    const int s = g + 15 * j;
    // tid==255 (g==15,m==0) duplicates (g=0,j+1); s==67 row has only 52 cols (m<13)
    const bool act = (tid < 255) && (s < MM) && (s < MM - 1 || m < 13);
    const int scol = s * MM + l4;
    f4 R0, R1, R2, R3, bv;
    if (act) {
      R0 = *(const f4*)(R + (size_t)(l4 + 0) * (MM * MM) + (size_t)s * MM);
      R1 = *(const f4*)(R + (size_t)(l4 + 1) * (MM * MM) + (size_t)s * MM);
      R2 = *(const f4*)(R + (size_t)(l4 + 2) * (MM * MM) + (size_t)s * MM);
      R3 = *(const f4*)(R + (size_t)(l4 + 3) * (MM * MM) + (size_t)s * MM);
      bv = *(const f4*)(bias + scol);
    }
#pragma unroll 2
    for (int t = 0; t < TT2; ++t) {
      if (act) {
        const float* t1p = t1s + t * T1W + l4;
        f4 a0 = *(const f4*)(t1p);
        f4 a1 = *(const f4*)(t1p + MM);
        f4 a2 = *(const f4*)(t1p + 2 * MM);
        f4 a3 = *(const f4*)(t1p + 3 * MM);
        f4 o;
        o.x = fmaf(a3.x, R0.w, fmaf(a2.x, R0.z, fmaf(a1.x, R0.y, fmaf(a0.x, R0.x, bv.x))));
        o.y = fmaf(a3.y, R1.w, fmaf(a2.y, R1.z, fmaf(a1.y, R1.y, fmaf(a0.y, R1.x, bv.y))));
        o.z = fmaf(a3.z, R2.w, fmaf(a2.z, R2.z, fmaf(a1.z, R2.y, fmaf(a0.z, R2.x, bv.z))));
        o.w = fmaf(a3.w, R3.w, fmaf(a2.w, R3.z, fmaf(a1.w, R3.y, fmaf(a0.w, R3.x, bv.w))));
        *(f4*)(out + (tb + t) * OUT_D + scol) = o;
      }
    }
  }
}

// ---------------- fused fallback (ws too small; round-7 body) ----------------
__global__ __launch_bounds__(NTH2, 2)
void monarch_fused(const float* __restrict__ x, const float* __restrict__ L,
                   const float* __restrict__ R, const float* __restrict__ bias,
                   float* __restrict__ out)
{
  __shared__ float t1s[TT2 * T1W];
  const int tid = threadIdx.x;
  const long tb = (long)blockIdx.x * TT2;
  const int g  = tid / 17;
  const int m  = tid - g * 17;
  const int l4 = 4 * m;

  for (int idx = tid; idx < T1W; idx += NTH2) {
    const int r = idx / MM;
    const float* Lp = L + (size_t)idx * MM;
    const float* xp = x + tb * IN_D + r * MM;
    const int p4max = (r == 3) ? (IN_D - 3 * MM) / 4 : MM / 4;
    float acc[TT2];
#pragma unroll
    for (int t = 0; t < TT2; ++t) acc[t] = 0.f;
    for (int p4 = 0; p4 < p4max; ++p4) {
      f4 Lv = *(const f4*)(Lp + p4 * 4);
#pragma unroll
      for (int t = 0; t < TT2; ++t) {
        f4 xv = *(const f4*)(xp + (size_t)t * IN_D + p4 * 4);
        acc[t] = fmaf(Lv.x, xv.x, acc[t]);
        acc[t] = fmaf(Lv.y, xv.y, acc[t]);
        acc[t] = fmaf(Lv.z, xv.z, acc[t]);
        acc[t] = fmaf(Lv.w, xv.w, acc[t]);
      }
    }
#pragma unroll
    for (int t = 0; t < TT2; ++t) t1s[t * T1W + idx] = acc[t];
  }
  __syncthreads();

#pragma unroll 1
  for (int j = 0; j < NJ; ++j) {
    const int s = g + 15 * j;
    const bool act = (tid < 255) && (s < MM) && (s < MM - 1 || m < 13);
    const int scol = s * MM + l4;
    f4 R0, R1, R2, R3, bv;
    if (act) {
      R0 = *(const f4*)(R + (size_t)(l4 + 0) * (MM * MM) + (size_t)s * MM);
      R1 = *(const f4*)(R + (size_t)(l4 + 1) * (MM * MM) + (size_t)s * MM);
      R2 = *(const f4*)(R + (size_t)(l4 + 2) * (MM * MM) + (size_t)s * MM);
      R3 = *(const f4*)(R + (size_t)(l4 + 3) * (MM * MM) + (size_t)s * MM);
      bv = *(const f4*)(bias + scol);
    }
#pragma unroll 2
    for (int t = 0; t < TT2; ++t) {
      if (act) {
        const float* t1p = t1s + t * T1W + l4;
        f4 a0 = *(const f4*)(t1p);
        f4 a1 = *(const f4*)(t1p + MM);
        f4 a2 = *(const f4*)(t1p + 2 * MM);
        f4 a3 = *(const f4*)(t1p + 3 * MM);
        f4 o;
        o.x = fmaf(a3.x, R0.w, fmaf(a2.x, R0.z, fmaf(a1.x, R0.y, fmaf(a0.x, R0.x, bv.x))));
        o.y = fmaf(a3.y, R1.w, fmaf(a2.y, R1.z, fmaf(a1.y, R1.y, fmaf(a0.y, R1.x, bv.y))));
        o.z = fmaf(a3.z, R2.w, fmaf(a2.z, R2.z, fmaf(a1.z, R2.y, fmaf(a0.z, R2.x, bv.z))));
        o.w = fmaf(a3.w, R3.w, fmaf(a2.w, R3.z, fmaf(a1.w, R3.y, fmaf(a0.w, R3.x, bv.w))));
        *(f4*)(out + (tb + t) * OUT_D + scol) = o;
      }
    }
  }
}

extern "C" void kernel_launch(void* const* d_in, const int* in_sizes, int n_in,
                              void* d_out, int out_size, void* d_ws, size_t ws_size,
                              hipStream_t stream) {
  const float* x    = (const float*)d_in[0];
  const float* L    = (const float*)d_in[1];
  const float* R    = (const float*)d_in[2];
  const float* bias = (const float*)d_in[3];
  float* out = (float*)d_out;

  const int ntok   = in_sizes[0] / IN_D;                    // 16384
  const size_t t1b = (size_t)ntok * T1W * sizeof(float);    // 17.8 MB

  if (ws_size >= t1b) {
    float* t1ws = (float*)d_ws;
    monarch_s1<<<ntok / TT1, NTH1, 0, stream>>>(x, L, t1ws);
    monarch_s2<<<ntok / TT2, NTH2, 0, stream>>>(t1ws, R, bias, out);
  } else {
    monarch_fused<<<ntok / TT2, NTH2, 0, stream>>>(x, L, R, bias, out);
  }
}

// Round 12
// 104.855 us; speedup vs baseline: 6.3308x; 1.6154x over previous
//
#include <hip/hip_runtime.h>

// MonarchLinear: x[16384,256] fp32, L[68,68,68], R[68,68,68], bias[4608] -> out[16384,4608] fp32.
//   t1[b,r,l] = sum_p x[b, r*68+p] * L[r,l,p]           (r<4; r==3 only p<52 valid)
//   out[b, s*68+l] = sum_{r<4} t1[b,r,l] * R[l,s,r] + bias[s*68+l]
//
// Round 12: ONE fused kernel. Facts: stage2 body = 46.6us = write roofline
// (round-8 rep measurement); stage1 FMA cost is only ~4us — every slow stage1
// was spill (r9/r10: VGPR cap 64 < 68-reg x array -> 300+MB scratch traffic) or
// latency starvation (r11: 2.5 waves/SIMD). This phase A: thread=(tok,r,lq),
// r/lq WAVE-UNIFORM (x,L loads are 16-lane broadcasts, <=16 addrs/instr);
// x segment LDS->xr[17] f4 regs ONCE (constant-indexed unroll); L from global
// (L2-hot, reused x16 lanes in-instr). launch_bounds(256,2): 256-reg ceiling,
// no forced spill; ~105 VGPR -> 4 waves/EU, LDS 34.3KB -> 4 blocks/CU.

typedef float f4 __attribute__((ext_vector_type(4)));

namespace {
constexpr int MM    = 68;
constexpr int IN_D  = 256;
constexpr int OUT_D = 4608;
constexpr int TT    = 16;              // tokens per block
constexpr int NTH   = 256;
constexpr int NJ    = 5;
constexpr int XROW  = IN_D + 4;        // 260 floats: x row stride in LDS
constexpr int TPAD  = 4 * MM + 4;      // 276 floats: t1 row stride (16B-aligned rows)
}

// phase-A dot worker: P4 compile-time so xr[] stays in registers.
template <int P4>
__device__ __forceinline__ void phaseA(const float* __restrict__ xls,
                                       const float* __restrict__ Lrow0,
                                       float* __restrict__ t1w)
{
  f4 xr[P4];
#pragma unroll
  for (int p4 = 0; p4 < P4; ++p4) xr[p4] = *(const f4*)(xls + 4 * p4);

#pragma unroll 1                        // li rolled: keeps live set small
  for (int li = 0; li < 17; ++li) {
    const float* Lp = Lrow0 + (size_t)li * MM;
    f4 s4 = {0.f, 0.f, 0.f, 0.f};
#pragma unroll
    for (int p4 = 0; p4 < P4; ++p4) {
      f4 Lv = *(const f4*)(Lp + 4 * p4);   // 16-lane broadcast, L2-hot
      s4.x = fmaf(xr[p4].x, Lv.x, s4.x);
      s4.y = fmaf(xr[p4].y, Lv.y, s4.y);
      s4.z = fmaf(xr[p4].z, Lv.z, s4.z);
      s4.w = fmaf(xr[p4].w, Lv.w, s4.w);
    }
    t1w[li] = (s4.x + s4.y) + (s4.z + s4.w);
  }
}

__global__ __launch_bounds__(NTH, 2)
void monarch_fused(const float* __restrict__ x, const float* __restrict__ L,
                   const float* __restrict__ R, const float* __restrict__ bias,
                   float* __restrict__ out)
{
  __shared__ float xs[TT * XROW];        // 16,640 B
  __shared__ float t1s[TT * TPAD];       // 17,664 B  (34.3 KB total -> 4 blk/CU)
  const int tid = threadIdx.x;
  const long tb = (long)blockIdx.x * TT;

  // ---- stage x -> LDS: 16 rows x 64 f4, 4 full-width coalesced sweeps ----
#pragma unroll
  for (int k = 0; k < (TT * IN_D / 4) / NTH; ++k) {
    int i   = k * NTH + tid;
    int tok = i >> 6;                    // wave-uniform
    int pos = i & 63;
    *(f4*)(&xs[tok * XROW + 4 * pos]) = *(const f4*)(x + (tb + tok) * IN_D + 4 * pos);
  }
  __syncthreads();

  // ---- phase A: t1[tok][r*68 + lq*17 + li] ----
  {
    const int tok = tid & 15;
    const int seg = tid >> 4;            // 0..15; wave = 4 segs, r WAVE-UNIFORM
    const int r   = seg >> 2;
    const int lq  = seg & 3;
    const float* xls   = &xs[tok * XROW + r * MM];
    const float* Lrow0 = L + (size_t)(r * MM + lq * 17) * MM;
    float*       t1w   = &t1s[tok * TPAD + r * MM + lq * 17];
    if (r < 3) phaseA<17>(xls, Lrow0, t1w);   // full 68-dot
    else       phaseA<13>(xls, Lrow0, t1w);   // r==3: only p<52 valid (x pad)
  }
  __syncthreads();

  // ---- phase B: proven round-7/8 stage-2 body (write roofline) ----
  {
    const int g  = tid / 17;
    const int m  = tid - g * 17;
    const int l4 = 4 * m;

#pragma unroll 1                         // j rolled: 20 hoisted regs per iter
    for (int j = 0; j < NJ; ++j) {
      const int s = g + 15 * j;
      // tid==255 (g==15,m==0) duplicates (g=0,j+1); s==67 row has only 52 cols (m<13)
      const bool act = (tid < 255) && (s < MM) && (s < MM - 1 || m < 13);
      const int scol = s * MM + l4;
      f4 R0, R1, R2, R3, bv;
      if (act) {
        R0 = *(const f4*)(R + (size_t)(l4 + 0) * (MM * MM) + (size_t)s * MM);
        R1 = *(const f4*)(R + (size_t)(l4 + 1) * (MM * MM) + (size_t)s * MM);
        R2 = *(const f4*)(R + (size_t)(l4 + 2) * (MM * MM) + (size_t)s * MM);
        R3 = *(const f4*)(R + (size_t)(l4 + 3) * (MM * MM) + (size_t)s * MM);
        bv = *(const f4*)(bias + scol);
      }
#pragma unroll 2
      for (int t = 0; t < TT; ++t) {
        if (act) {
          const float* t1p = t1s + t * TPAD + l4;
          f4 a0 = *(const f4*)(t1p);
          f4 a1 = *(const f4*)(t1p + MM);
          f4 a2 = *(const f4*)(t1p + 2 * MM);
          f4 a3 = *(const f4*)(t1p + 3 * MM);
          f4 o;
          o.x = fmaf(a3.x, R0.w, fmaf(a2.x, R0.z, fmaf(a1.x, R0.y, fmaf(a0.x, R0.x, bv.x))));
          o.y = fmaf(a3.y, R1.w, fmaf(a2.y, R1.z, fmaf(a1.y, R1.y, fmaf(a0.y, R1.x, bv.y))));
          o.z = fmaf(a3.z, R2.w, fmaf(a2.z, R2.z, fmaf(a1.z, R2.y, fmaf(a0.z, R2.x, bv.z))));
          o.w = fmaf(a3.w, R3.w, fmaf(a2.w, R3.z, fmaf(a1.w, R3.y, fmaf(a0.w, R3.x, bv.w))));
          *(f4*)(out + (tb + t) * OUT_D + scol) = o;
        }
      }
    }
  }
}

extern "C" void kernel_launch(void* const* d_in, const int* in_sizes, int n_in,
                              void* d_out, int out_size, void* d_ws, size_t ws_size,
                              hipStream_t stream) {
  const float* x    = (const float*)d_in[0];
  const float* L    = (const float*)d_in[1];
  const float* R    = (const float*)d_in[2];
  const float* bias = (const float*)d_in[3];
  float* out = (float*)d_out;

  const int ntok = in_sizes[0] / IN_D;     // 16384
  monarch_fused<<<ntok / TT, NTH, 0, stream>>>(x, L, R, bias, out);
}

// Round 13
// 91.383 us; speedup vs baseline: 7.2642x; 1.1474x over previous
//
#include <hip/hip_runtime.h>

// MonarchLinear: x[16384,256] fp32, L[68,68,68], R[68,68,68], bias[4608] -> out[16384,4608] fp32.
//   t1[b,r,l] = sum_p x[b, r*68+p] * L[r,l,p]           (r<4; r==3 only p<52 valid)
//   out[b, s*68+l] = sum_{r<4} t1[b,r,l] * R[l,s,r] + bias[s*68+l]
//
// Round 13: round-12 fused = 104.9us (phaseB alone = 46.6 = write roofline, so
// phaseA ~55us is NOT hiding under the store drain). Hiding needs 4 blocks/CU
// => VGPR <= 128; r12's launch_bounds(256,2) allowed 256 and xr[17]=68 regs
// likely pushed past 128 -> 2 blocks/CU, phases serialized. Fix:
//  (1) __launch_bounds__(256,4): VGPR cap 128, 4 blocks/CU (LDS 34.3KB fits).
//  (2) phase A split into two p-half passes (xr[9] then xr[8], disjoint lives,
//      ~60 live VGPR -> no spill possible at the 128 cap); pass 2 adds into LDS.
// Phase B = proven round-7/8 body verbatim.

typedef float f4 __attribute__((ext_vector_type(4)));

namespace {
constexpr int MM    = 68;
constexpr int IN_D  = 256;
constexpr int OUT_D = 4608;
constexpr int TT    = 16;              // tokens per block
constexpr int NTH   = 256;
constexpr int NJ    = 5;
constexpr int XROW  = IN_D + 4;        // 260 floats: x row stride in LDS
constexpr int TPAD  = 4 * MM + 4;      // 276 floats: t1 row stride (16B-aligned)
}

// phase-A dot worker, two passes over p so only ~9 f4 of x live at once.
template <int P4A, int P4B>
__device__ __forceinline__ void phaseA(const float* __restrict__ xls,
                                       const float* __restrict__ Lrow0,
                                       float* __restrict__ t1w)
{
  {                                      // pass 1: p4 in [0, P4A)
    f4 xr[P4A];
#pragma unroll
    for (int p4 = 0; p4 < P4A; ++p4) xr[p4] = *(const f4*)(xls + 4 * p4);
#pragma unroll 1
    for (int li = 0; li < 17; ++li) {
      const float* Lp = Lrow0 + (size_t)li * MM;
      f4 s4 = {0.f, 0.f, 0.f, 0.f};
#pragma unroll
      for (int p4 = 0; p4 < P4A; ++p4) {
        f4 Lv = *(const f4*)(Lp + 4 * p4);   // 16-lane broadcast, L2-hot
        s4.x = fmaf(xr[p4].x, Lv.x, s4.x);
        s4.y = fmaf(xr[p4].y, Lv.y, s4.y);
        s4.z = fmaf(xr[p4].z, Lv.z, s4.z);
        s4.w = fmaf(xr[p4].w, Lv.w, s4.w);
      }
      t1w[li] = (s4.x + s4.y) + (s4.z + s4.w);
    }
  }
  {                                      // pass 2: p4 in [P4A, P4A+P4B)
    f4 xr[P4B];
#pragma unroll
    for (int p4 = 0; p4 < P4B; ++p4) xr[p4] = *(const f4*)(xls + 4 * (P4A + p4));
#pragma unroll 1
    for (int li = 0; li < 17; ++li) {
      const float* Lp = Lrow0 + (size_t)li * MM + 4 * P4A;
      f4 s4 = {0.f, 0.f, 0.f, 0.f};
#pragma unroll
      for (int p4 = 0; p4 < P4B; ++p4) {
        f4 Lv = *(const f4*)(Lp + 4 * p4);
        s4.x = fmaf(xr[p4].x, Lv.x, s4.x);
        s4.y = fmaf(xr[p4].y, Lv.y, s4.y);
        s4.z = fmaf(xr[p4].z, Lv.z, s4.z);
        s4.w = fmaf(xr[p4].w, Lv.w, s4.w);
      }
      t1w[li] += (s4.x + s4.y) + (s4.z + s4.w);
    }
  }
}

__global__ __launch_bounds__(NTH, 4)     // VGPR cap 128; 4 blocks/CU for A/B overlap
void monarch_fused(const float* __restrict__ x, const float* __restrict__ L,
                   const float* __restrict__ R, const float* __restrict__ bias,
                   float* __restrict__ out)
{
  __shared__ float xs[TT * XROW];        // 16,640 B
  __shared__ float t1s[TT * TPAD];       // 17,664 B  (34.3 KB total)
  const int tid = threadIdx.x;
  const long tb = (long)blockIdx.x * TT;

  // ---- stage x -> LDS: 16 rows x 64 f4, 4 full-width coalesced sweeps ----
#pragma unroll
  for (int k = 0; k < (TT * IN_D / 4) / NTH; ++k) {
    int i   = k * NTH + tid;
    int tok = i >> 6;
    int pos = i & 63;
    *(f4*)(&xs[tok * XROW + 4 * pos]) = *(const f4*)(x + (tb + tok) * IN_D + 4 * pos);
  }
  __syncthreads();

  // ---- phase A: t1[tok][r*68 + lq*17 + li] ----
  {
    const int tok = tid & 15;
    const int seg = tid >> 4;            // 0..15; r,lq wave-uniform per 16 lanes
    const int r   = seg >> 2;
    const int lq  = seg & 3;
    const float* xls   = &xs[tok * XROW + r * MM];
    const float* Lrow0 = L + (size_t)(r * MM + lq * 17) * MM;
    float*       t1w   = &t1s[tok * TPAD + r * MM + lq * 17];
    if (r < 3) phaseA<9, 8>(xls, Lrow0, t1w);   // full 68-dot
    else       phaseA<9, 4>(xls, Lrow0, t1w);   // r==3: only p<52 valid
  }
  __syncthreads();

  // ---- phase B: proven round-7/8 stage-2 body (write roofline) ----
  {
    const int g  = tid / 17;
    const int m  = tid - g * 17;
    const int l4 = 4 * m;

#pragma unroll 1                         // j rolled: 20 hoisted regs per iter
    for (int j = 0; j < NJ; ++j) {
      const int s = g + 15 * j;
      // tid==255 (g==15,m==0) duplicates (g=0,j+1); s==67 row has only 52 cols (m<13)
      const bool act = (tid < 255) && (s < MM) && (s < MM - 1 || m < 13);
      const int scol = s * MM + l4;
      f4 R0, R1, R2, R3, bv;
      if (act) {
        R0 = *(const f4*)(R + (size_t)(l4 + 0) * (MM * MM) + (size_t)s * MM);
        R1 = *(const f4*)(R + (size_t)(l4 + 1) * (MM * MM) + (size_t)s * MM);
        R2 = *(const f4*)(R + (size_t)(l4 + 2) * (MM * MM) + (size_t)s * MM);
        R3 = *(const f4*)(R + (size_t)(l4 + 3) * (MM * MM) + (size_t)s * MM);
        bv = *(const f4*)(bias + scol);
      }
#pragma unroll 2
      for (int t = 0; t < TT; ++t) {
        if (act) {
          const float* t1p = t1s + t * TPAD + l4;
          f4 a0 = *(const f4*)(t1p);
          f4 a1 = *(const f4*)(t1p + MM);
          f4 a2 = *(const f4*)(t1p + 2 * MM);
          f4 a3 = *(const f4*)(t1p + 3 * MM);
          f4 o;
          o.x = fmaf(a3.x, R0.w, fmaf(a2.x, R0.z, fmaf(a1.x, R0.y, fmaf(a0.x, R0.x, bv.x))));
          o.y = fmaf(a3.y, R1.w, fmaf(a2.y, R1.z, fmaf(a1.y, R1.y, fmaf(a0.y, R1.x, bv.y))));
          o.z = fmaf(a3.z, R2.w, fmaf(a2.z, R2.z, fmaf(a1.z, R2.y, fmaf(a0.z, R2.x, bv.z))));
          o.w = fmaf(a3.w, R3.w, fmaf(a2.w, R3.z, fmaf(a1.w, R3.y, fmaf(a0.w, R3.x, bv.w))));
          *(f4*)(out + (tb + t) * OUT_D + scol) = o;
        }
      }
    }
  }
}

extern "C" void kernel_launch(void* const* d_in, const int* in_sizes, int n_in,
                              void* d_out, int out_size, void* d_ws, size_t ws_size,
                              hipStream_t stream) {
  const float* x    = (const float*)d_in[0];
  const float* L    = (const float*)d_in[1];
  const float* R    = (const float*)d_in[2];
  const float* bias = (const float*)d_in[3];
  float* out = (float*)d_out;

  const int ntok = in_sizes[0] / IN_D;     // 16384
  monarch_fused<<<ntok / TT, NTH, 0, stream>>>(x, L, R, bias, out);
}